// Round 1
// baseline (3141.539 us; speedup 1.0000x reference)
//
#include <hip/hip_runtime.h>

#define BB 64
#define TT 72
#define SS 72
#define EE 128
#define HH 256
#define VV 32000
#define KK 512  // 2H

using f32x4  = __attribute__((ext_vector_type(4))) float;
using short8 = __attribute__((ext_vector_type(8))) short;

__device__ __forceinline__ unsigned short f2bf(float f) {
  unsigned u = __float_as_uint(f);
  unsigned r = (u + 0x7fffu + ((u >> 16) & 1u)) >> 16;
  return (unsigned short)r;
}

__device__ __forceinline__ float sigm(float x) { return 1.f / (1.f + __expf(-x)); }
__device__ __forceinline__ float tanh_f(float x) { return 1.f - 2.f / (__expf(2.f * x) + 1.f); }

__device__ __forceinline__ float wsum(float v) {
  v += __shfl_xor(v, 1, 64);  v += __shfl_xor(v, 2, 64);  v += __shfl_xor(v, 4, 64);
  v += __shfl_xor(v, 8, 64);  v += __shfl_xor(v, 16, 64); v += __shfl_xor(v, 32, 64);
  return v;
}
__device__ __forceinline__ float wmax(float v) {
  v = fmaxf(v, __shfl_xor(v, 1, 64));  v = fmaxf(v, __shfl_xor(v, 2, 64));
  v = fmaxf(v, __shfl_xor(v, 4, 64));  v = fmaxf(v, __shfl_xor(v, 8, 64));
  v = fmaxf(v, __shfl_xor(v, 16, 64)); v = fmaxf(v, __shfl_xor(v, 32, 64));
  return v;
}

__device__ __forceinline__ void g2l16(const void* g, void* l) {
  __builtin_amdgcn_global_load_lds((const __attribute__((address_space(1))) void*)g,
                                   (__attribute__((address_space(3))) void*)l, 16, 0, 0);
}

// -------------------------------------------------------------------------
// W_lin fp32 -> bf16
// -------------------------------------------------------------------------
__global__ void cvt_kernel(const float* __restrict__ src, unsigned short* __restrict__ dst,
                           int n4) {
  int i = blockIdx.x * blockDim.x + threadIdx.x;
  const int stride = gridDim.x * blockDim.x;
  for (; i < n4; i += stride) {
    float4 v = ((const float4*)src)[i];
    ushort4 o;
    o.x = f2bf(v.x); o.y = f2bf(v.y); o.z = f2bf(v.z); o.w = f2bf(v.w);
    ((ushort4*)dst)[i] = o;
  }
}

// -------------------------------------------------------------------------
// Phase 1: sequential LSTM + attention. One block per batch row.
// 1024 threads: thread (j = tid>>2, kq = tid&3) owns gates {i,f,g,o}[j]
// over K-slice kq: x[kq*32..+32), h[kq*64..+64). W held in registers
// (384 fp32 VGPRs/thread). Recurrence in fp32; outputs h,ctx as bf16.
// -------------------------------------------------------------------------
__launch_bounds__(1024, 1)
__global__ void phase1_kernel(const int* __restrict__ tok, const float* __restrict__ enc,
                              const int* __restrict__ lens, const float* __restrict__ h0,
                              const float* __restrict__ c0, const float* __restrict__ emb,
                              const float* __restrict__ Wih, const float* __restrict__ Whh,
                              const float* __restrict__ bih, const float* __restrict__ bhh,
                              unsigned short* __restrict__ hcat) {
  __shared__ __align__(16) float enc_s[SS * HH];  // 73728 B
  __shared__ __align__(16) float x_s[EE];
  __shared__ __align__(16) float h_s[HH];
  __shared__ __align__(16) float at_s[SS];

  const int b   = blockIdx.x;
  const int tid = threadIdx.x;
  const int j   = tid >> 2;
  const int kq  = tid & 3;
  const int wv  = tid >> 6;
  const int ln  = tid & 63;

  // stage encoder slab for this batch row (reused all 72 steps)
  {
    const float4* src = (const float4*)(enc + (size_t)b * SS * HH);
    float4* dst = (float4*)enc_s;
    for (int i = tid; i < SS * HH / 4; i += 1024) dst[i] = src[i];
  }
  if (tid < HH / 4) ((float4*)h_s)[tid] = ((const float4*)(h0 + (size_t)b * HH))[tid];

  float c = c0[(size_t)b * HH + j];

  float bias[4];
#pragma unroll
  for (int g = 0; g < 4; ++g) {
    int row = g * HH + j;
    bias[g] = (kq == 0) ? (bih[row] + bhh[row]) : 0.f;
  }

  // weights -> registers (static indexing only; must stay in VGPRs)
  float4 wx4[32];
  float4 wh4[64];
#pragma unroll
  for (int g = 0; g < 4; ++g) {
    const float4* p = (const float4*)(Wih + (size_t)(g * HH + j) * EE) + kq * 8;
#pragma unroll
    for (int i = 0; i < 8; ++i) wx4[g * 8 + i] = p[i];
    const float4* q = (const float4*)(Whh + (size_t)(g * HH + j) * HH) + kq * 16;
#pragma unroll
    for (int i = 0; i < 16; ++i) wh4[g * 16 + i] = q[i];
  }

  const int len = lens[b];
  unsigned short* orow = hcat + (size_t)b * TT * KK;

  for (int t = 0; t < TT; ++t) {
    // stage x = emb[tok[b,t]]
    if (tid < EE / 4) {
      const int tk = tok[b * TT + t];
      ((float4*)x_s)[tid] = ((const float4*)(emb + (size_t)tk * EE))[tid];
    }
    __syncthreads();  // [A] x_s (and h_s) ready

    float a0 = bias[0], a1 = bias[1], a2 = bias[2], a3 = bias[3];
    {
      const float4* xp = (const float4*)x_s + kq * 8;
#pragma unroll
      for (int i = 0; i < 8; ++i) {
        float4 xv = xp[i];
        a0 += xv.x * wx4[i].x      + xv.y * wx4[i].y      + xv.z * wx4[i].z      + xv.w * wx4[i].w;
        a1 += xv.x * wx4[8 + i].x  + xv.y * wx4[8 + i].y  + xv.z * wx4[8 + i].z  + xv.w * wx4[8 + i].w;
        a2 += xv.x * wx4[16 + i].x + xv.y * wx4[16 + i].y + xv.z * wx4[16 + i].z + xv.w * wx4[16 + i].w;
        a3 += xv.x * wx4[24 + i].x + xv.y * wx4[24 + i].y + xv.z * wx4[24 + i].z + xv.w * wx4[24 + i].w;
      }
      const float4* hp = (const float4*)h_s + kq * 16;
#pragma unroll
      for (int i = 0; i < 16; ++i) {
        float4 hv = hp[i];
        a0 += hv.x * wh4[i].x      + hv.y * wh4[i].y      + hv.z * wh4[i].z      + hv.w * wh4[i].w;
        a1 += hv.x * wh4[16 + i].x + hv.y * wh4[16 + i].y + hv.z * wh4[16 + i].z + hv.w * wh4[16 + i].w;
        a2 += hv.x * wh4[32 + i].x + hv.y * wh4[32 + i].y + hv.z * wh4[32 + i].z + hv.w * wh4[32 + i].w;
        a3 += hv.x * wh4[48 + i].x + hv.y * wh4[48 + i].y + hv.z * wh4[48 + i].z + hv.w * wh4[48 + i].w;
      }
    }
    // reduce partial sums across the 4 kq lanes (bits 0..1 of lane id)
    a0 += __shfl_xor(a0, 1, 64); a0 += __shfl_xor(a0, 2, 64);
    a1 += __shfl_xor(a1, 1, 64); a1 += __shfl_xor(a1, 2, 64);
    a2 += __shfl_xor(a2, 1, 64); a2 += __shfl_xor(a2, 2, 64);
    a3 += __shfl_xor(a3, 1, 64); a3 += __shfl_xor(a3, 2, 64);

    const float ig = sigm(a0);
    const float fg = sigm(a1);
    const float gg = tanh_f(a2);
    const float og = sigm(a3);
    c = fg * c + ig * gg;
    const float hn = og * tanh_f(c);

    __syncthreads();  // [B] all reads of h_s done before overwrite
    if (kq == 0) {
      h_s[j] = hn;
      orow[(size_t)t * KK + j] = f2bf(hn);
    }
    __syncthreads();  // [C] h_s now holds h_new

    // scores[s] = (h_new . enc[s]) / 16 ; one wave per s
    {
      const float4 hv = ((const float4*)h_s)[ln];
      for (int s = wv; s < SS; s += 16) {
        const float4 ev = ((const float4*)(enc_s + s * HH))[ln];
        float p = hv.x * ev.x + hv.y * ev.y + hv.z * ev.z + hv.w * ev.w;
        p = wsum(p);
        if (ln == 0) at_s[s] = p * 0.0625f;
      }
    }
    __syncthreads();  // [D]

    // masked softmax over 72 scores (wave 0)
    if (wv == 0) {
      const float v0 = (ln < len) ? at_s[ln] : -3.0e38f;
      const bool has1 = (ln < 8) && (64 + ln < len);
      const float v1 = has1 ? at_s[64 + ln] : -3.0e38f;
      const float m = wmax(fmaxf(v0, v1));
      const float e0 = (ln < len) ? __expf(v0 - m) : 0.f;
      const float e1 = has1 ? __expf(v1 - m) : 0.f;
      const float inv = 1.f / wsum(e0 + e1);
      at_s[ln] = e0 * inv;
      if (ln < 8) at_s[64 + ln] = e1 * inv;
    }
    __syncthreads();  // [E] attn ready

    // ctx[d] = sum_s attn[s] * enc[s][d]
    if (tid < HH) {
      float acc = 0.f;
      for (int s = 0; s < len; ++s) acc += at_s[s] * enc_s[s * HH + tid];
      orow[(size_t)t * KK + HH + tid] = f2bf(acc);
    }
    // next iteration's x-stage is fenced from this step's readers by [A]
  }
}

// -------------------------------------------------------------------------
// Phase 2: out[m][n] = sum_k hcat[m][k] * wlin16[n][k] + b_lin[n]
// m97-style 128x128 tile, BK=32, 4 waves, global_load_lds(16B),
// mfma_f32_16x16x32_bf16, fp32 epilogue with bias.
// M = 4608 = 36*128, N = 32000 = 250*128, K = 512 = 16*32 (no edges).
// -------------------------------------------------------------------------
__launch_bounds__(256)
__global__ void gemm_kernel(const unsigned short* __restrict__ A,
                            const unsigned short* __restrict__ Bw,
                            const float* __restrict__ blin,
                            float* __restrict__ out) {
  __shared__ __align__(16) unsigned short As[128 * 32];
  __shared__ __align__(16) unsigned short Bs[128 * 32];

  const int bid = blockIdx.x;
  const int mt = bid % 36;       // m fast: same-n blocks land round-robin on the
  const int nt = bid / 36;       // 8 XCDs -> each XCD keeps its B n-slab L2-hot
  const int m0 = mt * 128, n0 = nt * 128;
  const int tid = threadIdx.x;
  const int ln = tid & 63;
  const int w  = tid >> 6;
  const int wm = w >> 1, wn = w & 1;  // 64x64 quadrant per wave

  const char* Ab = (const char*)(A + (size_t)m0 * KK);
  const char* Bb = (const char*)(Bw + (size_t)n0 * KK);

  const int o0 = tid * 16;       // LDS byte offset, round 0
  const int o1 = o0 + 4096;      // round 1
  const int r0 = o0 >> 6, c0b = o0 & 63;  // tile row / byte-in-row (64 B rows)
  const int r1 = o1 >> 6, c1b = o1 & 63;

  f32x4 acc[4][4] = {};

  float bs[4];
#pragma unroll
  for (int fn = 0; fn < 4; ++fn) bs[fn] = blin[n0 + wn * 64 + fn * 16 + (ln & 15)];

  for (int kt = 0; kt < 16; ++kt) {
    const int kb = kt * 64;  // byte offset of this K-chunk within a row
    g2l16(Ab + (size_t)r0 * (KK * 2) + kb + c0b, (char*)As + o0);
    g2l16(Ab + (size_t)r1 * (KK * 2) + kb + c1b, (char*)As + o1);
    g2l16(Bb + (size_t)r0 * (KK * 2) + kb + c0b, (char*)Bs + o0);
    g2l16(Bb + (size_t)r1 * (KK * 2) + kb + c1b, (char*)Bs + o1);
    __syncthreads();  // compiler drains vmcnt(0) before s_barrier

    short8 af[4], bf[4];
#pragma unroll
    for (int f = 0; f < 4; ++f) {
      af[f] = *(const short8*)&As[(wm * 64 + f * 16 + (ln & 15)) * 32 + (ln >> 4) * 8];
      bf[f] = *(const short8*)&Bs[(wn * 64 + f * 16 + (ln & 15)) * 32 + (ln >> 4) * 8];
    }
#pragma unroll
    for (int fm = 0; fm < 4; ++fm)
#pragma unroll
      for (int fn = 0; fn < 4; ++fn)
        acc[fm][fn] = __builtin_amdgcn_mfma_f32_16x16x32_bf16(af[fm], bf[fn], acc[fm][fn], 0, 0, 0);
    __syncthreads();
  }

#pragma unroll
  for (int fm = 0; fm < 4; ++fm) {
    const int mrow = m0 + wm * 64 + fm * 16 + (ln >> 4) * 4;
#pragma unroll
    for (int fn = 0; fn < 4; ++fn) {
      const int n = n0 + wn * 64 + fn * 16 + (ln & 15);
      float* cp = out + (size_t)mrow * VV + n;
#pragma unroll
      for (int r = 0; r < 4; ++r) cp[(size_t)r * VV] = acc[fm][fn][r] + bs[fn];
    }
  }
}

// -------------------------------------------------------------------------
extern "C" void kernel_launch(void* const* d_in, const int* in_sizes, int n_in,
                              void* d_out, int out_size, void* d_ws, size_t ws_size,
                              hipStream_t stream) {
  const int*   tok  = (const int*)  d_in[0];
  const float* enc  = (const float*)d_in[1];
  const int*   lens = (const int*)  d_in[2];
  const float* h0   = (const float*)d_in[3];
  const float* c0   = (const float*)d_in[4];
  const float* emb  = (const float*)d_in[5];
  const float* Wih  = (const float*)d_in[6];
  const float* Whh  = (const float*)d_in[7];
  const float* bih  = (const float*)d_in[8];
  const float* bhh  = (const float*)d_in[9];
  const float* Wlin = (const float*)d_in[10];
  const float* blin = (const float*)d_in[11];

  // ws layout: [0, 4.72 MB) hcat bf16 (4608 x 512); [5 MB, +32.77 MB) W_lin bf16
  unsigned short* hcat   = (unsigned short*)d_ws;
  unsigned short* wlin16 = (unsigned short*)((char*)d_ws + (5u << 20));
  float* out = (float*)d_out;

  cvt_kernel<<<2048, 256, 0, stream>>>(Wlin, wlin16, (VV * KK) / 4);
  phase1_kernel<<<BB, 1024, 0, stream>>>(tok, enc, lens, h0, c0, emb,
                                         Wih, Whh, bih, bhh, hcat);
  gemm_kernel<<<36 * 250, 256, 0, stream>>>(hcat, wlin16, blin, out);
}

// Round 2
// 964.488 us; speedup vs baseline: 3.2572x; 3.2572x over previous
//
#include <hip/hip_runtime.h>

#define BB 64
#define TT 72
#define SS 72
#define EE 128
#define HH 256
#define VV 32000
#define KK 512
#define NB 8    // lstm blocks
#define JB 32   // j-slice per lstm block

using f32x4  = __attribute__((ext_vector_type(4))) float;
using short8 = __attribute__((ext_vector_type(8))) short;

__device__ __forceinline__ unsigned short f2bf(float f) {
  unsigned u = __float_as_uint(f);
  unsigned r = (u + 0x7fffu + ((u >> 16) & 1u)) >> 16;
  return (unsigned short)r;
}
__device__ __forceinline__ float sigm(float x) { return 1.f / (1.f + __expf(-x)); }
__device__ __forceinline__ float tanh_f(float x) { return 1.f - 2.f / (__expf(2.f * x) + 1.f); }

__device__ __forceinline__ float wsum(float v) {
  v += __shfl_xor(v, 1, 64);  v += __shfl_xor(v, 2, 64);  v += __shfl_xor(v, 4, 64);
  v += __shfl_xor(v, 8, 64);  v += __shfl_xor(v, 16, 64); v += __shfl_xor(v, 32, 64);
  return v;
}
__device__ __forceinline__ float wmax(float v) {
  v = fmaxf(v, __shfl_xor(v, 1, 64));  v = fmaxf(v, __shfl_xor(v, 2, 64));
  v = fmaxf(v, __shfl_xor(v, 4, 64));  v = fmaxf(v, __shfl_xor(v, 8, 64));
  v = fmaxf(v, __shfl_xor(v, 16, 64)); v = fmaxf(v, __shfl_xor(v, 32, 64));
  return v;
}
__device__ __forceinline__ void g2l16(const void* g, void* l) {
  __builtin_amdgcn_global_load_lds((const __attribute__((address_space(1))) void*)g,
                                   (__attribute__((address_space(3))) void*)l, 16, 0, 0);
}

// ------------------------------------------------------------------ cvt
__global__ void cvt_kernel(const float* __restrict__ src, unsigned short* __restrict__ dst,
                           int n4) {
  int i = blockIdx.x * blockDim.x + threadIdx.x;
  const int stride = gridDim.x * blockDim.x;
  for (; i < n4; i += stride) {
    float4 v = ((const float4*)src)[i];
    ushort4 o;
    o.x = f2bf(v.x); o.y = f2bf(v.y); o.z = f2bf(v.z); o.w = f2bf(v.w);
    ((ushort4*)dst)[i] = o;
  }
}

// ------------------------------------------------------------------ gather x = emb[tok] -> bf16, layout [t][b][128]
__global__ void gather_kernel(const int* __restrict__ tok, const float* __restrict__ emb,
                              unsigned int* __restrict__ xemb) {
  const int gidx = blockIdx.x * 256 + threadIdx.x;   // [0, 72*64*64)
  if (gidx >= TT * BB * 64) return;
  const int row = gidx >> 6;          // t*64 + b
  const int c   = gidx & 63;
  const int t = row >> 6, b = row & 63;
  const int tk = tok[b * TT + t];
  const float2 v = ((const float2*)(emb + (size_t)tk * EE))[c];
  xemb[gidx] = f2bf(v.x) | ((unsigned)f2bf(v.y) << 16);
}

// ------------------------------------------------------------------ lstm (sequential, weights-stationary)
// 8 blocks x 256 threads. Block bk owns j in [32bk, 32bk+32). Wave g (0..3)
// owns gate g. B-frags (bf16 weights, K=384 = [Whh(256) | Wih(128)]) live in
// VGPRs all 72 steps. h exchanged via per-step buffers + device-scope atomics.
__launch_bounds__(256, 1)
__global__ void lstm_kernel(const float* __restrict__ h0, const float* __restrict__ c0,
                            const float* __restrict__ Wih, const float* __restrict__ Whh,
                            const float* __restrict__ bih, const float* __restrict__ bhh,
                            const unsigned short* __restrict__ xemb,
                            unsigned int* __restrict__ hex,      // 73 * 64 rows * 128 u32
                            unsigned int* __restrict__ flags,    // 73 counters (memset 0)
                            unsigned short* __restrict__ hcat,   // [b][t][512], h-half
                            float* __restrict__ hstore) {        // [t][b][256] fp32
  __shared__ __align__(16) unsigned short h_lds[BB * HH];  // 32 KB, XOR-swizzled 16B slots
  __shared__ __align__(16) unsigned short x_lds[BB * EE];  // 16 KB
  __shared__ __align__(16) float gates[BB * 128];          // 32 KB

  const int bk  = blockIdx.x;
  const int tid = threadIdx.x;
  const int ln  = tid & 63;
  const int g   = tid >> 6;      // wave id == gate id
  const int n16 = ln & 15;
  const int kgrp = ln >> 4;

  // ---- weights -> register B-fragments (one-time) ----
  short8 wf[2][12];
  float biasv[2];
#pragma unroll
  for (int jj = 0; jj < 2; ++jj) {
    const int grow = g * HH + bk * JB + jj * 16 + n16;   // row in 4H gate space
    biasv[jj] = bih[grow] + bhh[grow];
#pragma unroll
    for (int kf = 0; kf < 12; ++kf) {
      const int kg = kf * 32 + kgrp * 8;
      const float* src = (kf < 8) ? (Whh + (size_t)grow * HH + kg)
                                  : (Wih + (size_t)grow * EE + (kg - 256));
      float4 v0 = ((const float4*)src)[0];
      float4 v1 = ((const float4*)src)[1];
      short8 w;
      w[0]=(short)f2bf(v0.x); w[1]=(short)f2bf(v0.y); w[2]=(short)f2bf(v0.z); w[3]=(short)f2bf(v0.w);
      w[4]=(short)f2bf(v1.x); w[5]=(short)f2bf(v1.y); w[6]=(short)f2bf(v1.z); w[7]=(short)f2bf(v1.w);
      wf[jj][kf] = w;
    }
  }

  // ---- epilogue ownership + c init ----
  const int jp = tid & 15;       // j pair index (j = 2jp, 2jp+1)
  const int bq = tid >> 4;       // 0..15 -> 4 batches each
  float creg[4][2];
#pragma unroll
  for (int bb = 0; bb < 4; ++bb) {
    const int b = bq * 4 + bb;
    const int jg = bk * JB + jp * 2;
    creg[bb][0] = c0[(size_t)b * HH + jg];
    creg[bb][1] = c0[(size_t)b * HH + jg + 1];
  }

  // ---- h_ex[0] = bf16(h0); block bk writes batch rows [8bk, 8bk+8) ----
  {
    const int r = tid >> 5;            // 0..7
    const int b = bk * 8 + r;
    const int seg = tid & 31;          // 8-element segment
    const float4 u0 = ((const float4*)(h0 + (size_t)b * HH + seg * 8))[0];
    const float4 u1 = ((const float4*)(h0 + (size_t)b * HH + seg * 8))[1];
    unsigned int w[4];
    w[0] = f2bf(u0.x) | ((unsigned)f2bf(u0.y) << 16);
    w[1] = f2bf(u0.z) | ((unsigned)f2bf(u0.w) << 16);
    w[2] = f2bf(u1.x) | ((unsigned)f2bf(u1.y) << 16);
    w[3] = f2bf(u1.z) | ((unsigned)f2bf(u1.w) << 16);
    unsigned int* dst = hex + (size_t)b * 128 + seg * 4;
#pragma unroll
    for (int q = 0; q < 4; ++q)
      __hip_atomic_store(dst + q, w[q], __ATOMIC_RELAXED, __HIP_MEMORY_SCOPE_AGENT);
  }
  __syncthreads();
  if (tid == 0)
    __hip_atomic_fetch_add(flags, 1u, __ATOMIC_RELEASE, __HIP_MEMORY_SCOPE_AGENT);

  const int sb = tid >> 2;   // staging: batch row
  const int sc = tid & 3;    // staging: 128-B chunk within row

  for (int t = 0; t < TT; ++t) {
    if (tid == 0) {
      while (__hip_atomic_load(flags + t, __ATOMIC_ACQUIRE, __HIP_MEMORY_SCOPE_AGENT) < NB)
        __builtin_amdgcn_s_sleep(1);
    }
    __syncthreads();

    // ---- stage h (atomic, L2-bypassing) and x into swizzled LDS ----
    {
      const int swz = sb & 7;
      unsigned long long* hsrc =
          (unsigned long long*)(hex + (size_t)t * (BB * 128)) + (size_t)sb * 64 + sc * 16;
      uint4* hdst = (uint4*)h_lds;
#pragma unroll
      for (int s = 0; s < 8; ++s) {
        unsigned long long a = __hip_atomic_load(hsrc + 2*s,   __ATOMIC_RELAXED, __HIP_MEMORY_SCOPE_AGENT);
        unsigned long long b = __hip_atomic_load(hsrc + 2*s+1, __ATOMIC_RELAXED, __HIP_MEMORY_SCOPE_AGENT);
        uint4 v; v.x = (unsigned)a; v.y = (unsigned)(a >> 32);
        v.z = (unsigned)b; v.w = (unsigned)(b >> 32);
        hdst[sb * 32 + ((sc * 8 + s) ^ swz)] = v;
      }
      const uint4* xsrc = (const uint4*)(xemb + (size_t)t * (BB * EE)) + (size_t)sb * 16 + sc * 4;
      uint4* xdst = (uint4*)x_lds;
#pragma unroll
      for (int s = 0; s < 4; ++s)
        xdst[sb * 16 + ((sc * 4 + s) ^ swz)] = xsrc[s];
    }
    __syncthreads();

    // ---- MFMA: gates(64 x 128-slice) = [h,x] @ W^T + bias ----
    f32x4 acc[4][2];
#pragma unroll
    for (int mt = 0; mt < 4; ++mt)
#pragma unroll
      for (int jj = 0; jj < 2; ++jj)
        acc[mt][jj] = (f32x4){biasv[jj], biasv[jj], biasv[jj], biasv[jj]};

#pragma unroll
    for (int kf = 0; kf < 12; ++kf) {
#pragma unroll
      for (int mt = 0; mt < 4; ++mt) {
        const int b = mt * 16 + n16;
        const short8 a = (kf < 8)
          ? *(const short8*)&h_lds[b * HH + (((kf * 4 + kgrp) ^ (b & 7)) << 3)]
          : *(const short8*)&x_lds[b * EE + ((((kf - 8) * 4 + kgrp) ^ (b & 7)) << 3)];
        acc[mt][0] = __builtin_amdgcn_mfma_f32_16x16x32_bf16(a, wf[0][kf], acc[mt][0], 0, 0, 0);
        acc[mt][1] = __builtin_amdgcn_mfma_f32_16x16x32_bf16(a, wf[1][kf], acc[mt][1], 0, 0, 0);
      }
    }

    // ---- gates -> LDS (col = g*32 + jj*16 + n16) ----
#pragma unroll
    for (int mt = 0; mt < 4; ++mt)
#pragma unroll
      for (int jj = 0; jj < 2; ++jj)
#pragma unroll
        for (int r = 0; r < 4; ++r)
          gates[(mt * 16 + kgrp * 4 + r) * 128 + g * JB + jj * 16 + n16] = acc[mt][jj][r];
    __syncthreads();

    // ---- pointwise LSTM cell + outputs ----
    {
#pragma unroll
      for (int bb = 0; bb < 4; ++bb) {
        const int b = bq * 4 + bb;
        const float* gr = gates + b * 128 + jp * 2;
        const float i0 = gr[0],  i1 = gr[1];
        const float f0 = gr[32], f1 = gr[33];
        const float g0 = gr[64], g1 = gr[65];
        const float o0 = gr[96], o1 = gr[97];
        const float cA = sigm(f0) * creg[bb][0] + sigm(i0) * tanh_f(g0);
        const float cB = sigm(f1) * creg[bb][1] + sigm(i1) * tanh_f(g1);
        creg[bb][0] = cA; creg[bb][1] = cB;
        const float hA = sigm(o0) * tanh_f(cA);
        const float hB = sigm(o1) * tanh_f(cB);
        const unsigned int pk = f2bf(hA) | ((unsigned)f2bf(hB) << 16);
        __hip_atomic_store(hex + (size_t)(t + 1) * (BB * 128) + b * 128 + bk * 16 + jp,
                           pk, __ATOMIC_RELAXED, __HIP_MEMORY_SCOPE_AGENT);
        ((unsigned int*)hcat)[(size_t)(b * TT + t) * 256 + bk * 16 + jp] = pk;
        ((float2*)hstore)[(size_t)(t * BB + b) * 128 + bk * 16 + jp] = make_float2(hA, hB);
      }
    }
    __syncthreads();
    if (tid == 0)
      __hip_atomic_fetch_add(flags + t + 1, 1u, __ATOMIC_RELEASE, __HIP_MEMORY_SCOPE_AGENT);
  }
}

// ------------------------------------------------------------------ attention (fully parallel over (b,t))
__launch_bounds__(256)
__global__ void attn_kernel(const float* __restrict__ enc, const int* __restrict__ lens,
                            const float* __restrict__ hstore,
                            unsigned short* __restrict__ hcat) {
  __shared__ __align__(16) float enc_s[SS * HH];   // 72 KB
  __shared__ __align__(16) float h_s[HH];
  __shared__ float at_s[SS];

  const int b   = blockIdx.x >> 2;
  const int tq  = blockIdx.x & 3;
  const int tid = threadIdx.x;
  const int wv  = tid >> 6, ln = tid & 63;
  const int len = lens[b];

  {
    const float4* src = (const float4*)(enc + (size_t)b * SS * HH);
    float4* dst = (float4*)enc_s;
    for (int i = tid; i < SS * HH / 4; i += 256) dst[i] = src[i];
  }

  for (int ti = 0; ti < TT / 4; ++ti) {
    const int t = tq * (TT / 4) + ti;
    __syncthreads();   // enc_s ready / previous iteration fully done
    if (tid < 64) ((float4*)h_s)[tid] =
        ((const float4*)(hstore + (size_t)(t * BB + b) * HH))[tid];
    __syncthreads();

    const float4 hv = ((const float4*)h_s)[ln];
    for (int s = wv; s < SS; s += 4) {
      const float4 ev = ((const float4*)(enc_s + s * HH))[ln];
      float p = hv.x * ev.x + hv.y * ev.y + hv.z * ev.z + hv.w * ev.w;
      p = wsum(p);
      if (ln == 0) at_s[s] = p * 0.0625f;
    }
    __syncthreads();
    if (wv == 0) {
      const float v0 = (ln < len) ? at_s[ln] : -3.0e38f;
      const bool has1 = (ln < 8) && (64 + ln < len);
      const float v1 = has1 ? at_s[64 + ln] : -3.0e38f;
      const float m = wmax(fmaxf(v0, v1));
      const float e0 = (ln < len) ? __expf(v0 - m) : 0.f;
      const float e1 = has1 ? __expf(v1 - m) : 0.f;
      const float inv = 1.f / wsum(e0 + e1);
      at_s[ln] = e0 * inv;
      if (ln < 8) at_s[64 + ln] = e1 * inv;
    }
    __syncthreads();
    float acc = 0.f;
#pragma unroll 8
    for (int s = 0; s < SS; ++s) acc += at_s[s] * enc_s[s * HH + tid];
    hcat[(size_t)(b * TT + t) * KK + HH + tid] = f2bf(acc);
  }
}

// ------------------------------------------------------------------ vocab GEMM (m97-style, validated round 0)
__launch_bounds__(256)
__global__ void gemm_kernel(const unsigned short* __restrict__ A,
                            const unsigned short* __restrict__ Bw,
                            const float* __restrict__ blin,
                            float* __restrict__ out) {
  __shared__ __align__(16) unsigned short As[128 * 32];
  __shared__ __align__(16) unsigned short Bs[128 * 32];

  const int bid = blockIdx.x;
  const int mt = bid % 36;
  const int nt = bid / 36;
  const int m0 = mt * 128, n0 = nt * 128;
  const int tid = threadIdx.x;
  const int ln = tid & 63;
  const int w  = tid >> 6;
  const int wm = w >> 1, wn = w & 1;

  const char* Ab = (const char*)(A + (size_t)m0 * KK);
  const char* Bb = (const char*)(Bw + (size_t)n0 * KK);

  const int o0 = tid * 16;
  const int o1 = o0 + 4096;
  const int r0 = o0 >> 6, c0b = o0 & 63;
  const int r1 = o1 >> 6, c1b = o1 & 63;

  f32x4 acc[4][4] = {};

  float bs[4];
#pragma unroll
  for (int fn = 0; fn < 4; ++fn) bs[fn] = blin[n0 + wn * 64 + fn * 16 + (ln & 15)];

  for (int kt = 0; kt < 16; ++kt) {
    const int kb = kt * 64;
    g2l16(Ab + (size_t)r0 * (KK * 2) + kb + c0b, (char*)As + o0);
    g2l16(Ab + (size_t)r1 * (KK * 2) + kb + c1b, (char*)As + o1);
    g2l16(Bb + (size_t)r0 * (KK * 2) + kb + c0b, (char*)Bs + o0);
    g2l16(Bb + (size_t)r1 * (KK * 2) + kb + c1b, (char*)Bs + o1);
    __syncthreads();

    short8 af[4], bf[4];
#pragma unroll
    for (int f = 0; f < 4; ++f) {
      af[f] = *(const short8*)&As[(wm * 64 + f * 16 + (ln & 15)) * 32 + (ln >> 4) * 8];
      bf[f] = *(const short8*)&Bs[(wn * 64 + f * 16 + (ln & 15)) * 32 + (ln >> 4) * 8];
    }
#pragma unroll
    for (int fm = 0; fm < 4; ++fm)
#pragma unroll
      for (int fn = 0; fn < 4; ++fn)
        acc[fm][fn] = __builtin_amdgcn_mfma_f32_16x16x32_bf16(af[fm], bf[fn], acc[fm][fn], 0, 0, 0);
    __syncthreads();
  }

#pragma unroll
  for (int fm = 0; fm < 4; ++fm) {
    const int mrow = m0 + wm * 64 + fm * 16 + (ln >> 4) * 4;
#pragma unroll
    for (int fn = 0; fn < 4; ++fn) {
      const int n = n0 + wn * 64 + fn * 16 + (ln & 15);
      float* cp = out + (size_t)mrow * VV + n;
#pragma unroll
      for (int r = 0; r < 4; ++r) cp[(size_t)r * VV] = acc[fm][fn][r] + bs[fn];
    }
  }
}

// ------------------------------------------------------------------
extern "C" void kernel_launch(void* const* d_in, const int* in_sizes, int n_in,
                              void* d_out, int out_size, void* d_ws, size_t ws_size,
                              hipStream_t stream) {
  const int*   tok  = (const int*)  d_in[0];
  const float* enc  = (const float*)d_in[1];
  const int*   lens = (const int*)  d_in[2];
  const float* h0   = (const float*)d_in[3];
  const float* c0   = (const float*)d_in[4];
  const float* emb  = (const float*)d_in[5];
  const float* Wih  = (const float*)d_in[6];
  const float* Whh  = (const float*)d_in[7];
  const float* bih  = (const float*)d_in[8];
  const float* bhh  = (const float*)d_in[9];
  const float* Wlin = (const float*)d_in[10];
  const float* blin = (const float*)d_in[11];

  char* ws = (char*)d_ws;
  unsigned short* wlin16 = (unsigned short*)(ws);               // 32,768,000 B
  unsigned short* hcat   = (unsigned short*)(ws + 32768000);    //  4,718,592 B
  unsigned short* xemb   = (unsigned short*)(ws + 37486592);    //  1,179,648 B
  unsigned int*   hex    = (unsigned int*)  (ws + 38666240);    //  2,392,064 B (73 steps)
  unsigned int*   flags  = (unsigned int*)  (ws + 41058304);    //        512 B
  float* hstore = (float*)d_out;   // scratch in d_out's first 4.7 MB; gemm overwrites all of d_out
  float* out    = (float*)d_out;

  hipMemsetAsync(flags, 0, 512, stream);
  gather_kernel<<<(TT * BB * 64 + 255) / 256, 256, 0, stream>>>(tok, emb, (unsigned int*)xemb);
  lstm_kernel<<<NB, 256, 0, stream>>>(h0, c0, Wih, Whh, bih, bhh, xemb, hex, flags, hcat, hstore);
  attn_kernel<<<BB * 4, 256, 0, stream>>>(enc, lens, hstore, hcat);
  cvt_kernel<<<2048, 256, 0, stream>>>(Wlin, wlin16, (VV * KK) / 4);
  gemm_kernel<<<36 * 250, 256, 0, stream>>>(hcat, wlin16, blin, out);
}

// Round 3
// 948.416 us; speedup vs baseline: 3.3124x; 1.0169x over previous
//
#include <hip/hip_runtime.h>

#define BB 64
#define TT 72
#define SS 72
#define EE 128
#define HH 256
#define VV 32000
#define KK 512
#define NB 4     // lstm blocks (j-partition)

using f32x4  = __attribute__((ext_vector_type(4))) float;
using short8 = __attribute__((ext_vector_type(8))) short;

__device__ __forceinline__ unsigned short f2bf(float f) {
  unsigned u = __float_as_uint(f);
  unsigned r = (u + 0x7fffu + ((u >> 16) & 1u)) >> 16;
  return (unsigned short)r;
}
__device__ __forceinline__ float bf2f(unsigned short b) {
  return __uint_as_float(((unsigned)b) << 16);
}
__device__ __forceinline__ float sigm(float x) { return 1.f / (1.f + __expf(-x)); }
__device__ __forceinline__ float tanh_f(float x) { return 1.f - 2.f / (__expf(2.f * x) + 1.f); }

__device__ __forceinline__ float wsum(float v) {
  v += __shfl_xor(v, 1, 64);  v += __shfl_xor(v, 2, 64);  v += __shfl_xor(v, 4, 64);
  v += __shfl_xor(v, 8, 64);  v += __shfl_xor(v, 16, 64); v += __shfl_xor(v, 32, 64);
  return v;
}
__device__ __forceinline__ float wmax(float v) {
  v = fmaxf(v, __shfl_xor(v, 1, 64));  v = fmaxf(v, __shfl_xor(v, 2, 64));
  v = fmaxf(v, __shfl_xor(v, 4, 64));  v = fmaxf(v, __shfl_xor(v, 8, 64));
  v = fmaxf(v, __shfl_xor(v, 16, 64)); v = fmaxf(v, __shfl_xor(v, 32, 64));
  return v;
}
__device__ __forceinline__ void g2l16(const void* g, void* l) {
  __builtin_amdgcn_global_load_lds((const __attribute__((address_space(1))) void*)g,
                                   (__attribute__((address_space(3))) void*)l, 16, 0, 0);
}

// ------------------------------------------------------------------ cvt W_lin fp32->bf16
__global__ void cvt_kernel(const float* __restrict__ src, unsigned short* __restrict__ dst,
                           int n4) {
  int i = blockIdx.x * blockDim.x + threadIdx.x;
  const int stride = gridDim.x * blockDim.x;
  for (; i < n4; i += stride) {
    float4 v = ((const float4*)src)[i];
    ushort4 o;
    o.x = f2bf(v.x); o.y = f2bf(v.y); o.z = f2bf(v.z); o.w = f2bf(v.w);
    ((ushort4*)dst)[i] = o;
  }
}

// ------------------------------------------------------------------ gather x = emb[tok] -> bf16
// layout: xembt[t][kcx 0..15][b 0..63] 16B entries (entry = 8 consecutive k for one b)
__global__ void gather_kernel(const int* __restrict__ tok, const float* __restrict__ emb,
                              uint4* __restrict__ xembt) {
  const int e = blockIdx.x * 256 + threadIdx.x;
  if (e >= TT * 16 * 64) return;
  const int b = e & 63, kcx = (e >> 6) & 15, t = e >> 10;
  const int tk = tok[b * TT + t];
  const float4* s = (const float4*)(emb + (size_t)tk * EE + kcx * 8);
  const float4 v0 = s[0], v1 = s[1];
  uint4 o;
  o.x = f2bf(v0.x) | ((unsigned)f2bf(v0.y) << 16);
  o.y = f2bf(v0.z) | ((unsigned)f2bf(v0.w) << 16);
  o.z = f2bf(v1.x) | ((unsigned)f2bf(v1.y) << 16);
  o.w = f2bf(v1.z) | ((unsigned)f2bf(v1.w) << 16);
  xembt[e] = o;
}

// ------------------------------------------------------------------ lstm (sequential)
// 4 blocks x 512 threads. Block bk owns j in [64bk, 64bk+64) (256 gate-rows).
// Wave w owns 32 gate-rows: gate g = w>>1, jloc = (w&1)*32 + nt*16 + n16.
// Weight B-frags in VGPRs (96/thread). h/x in LDS as 16B [kchunk][b] entries.
// Exchange: plain stores -> vmcnt -> barrier -> RELEASE flag; peers poll 4 flags
// in parallel -> barrier -> ACQUIRE fence -> plain dwordx4 loads.
__launch_bounds__(512)
__global__ void lstm_kernel(const float* __restrict__ h0, const float* __restrict__ c0,
                            const float* __restrict__ Wih, const float* __restrict__ Whh,
                            const float* __restrict__ bih, const float* __restrict__ bhh,
                            const uint4* __restrict__ xembt,
                            uint4* __restrict__ hex,          // [73][32][64] 16B entries
                            unsigned int* __restrict__ flags) {
  __shared__ __align__(16) uint4 hx[48 * 64];     // 49152 B: kc 0..31 = h, 32..47 = x
  __shared__ float gates[64 * 260];               // 66560 B (stride 260 breaks conflicts)

  const int bk  = blockIdx.x;
  const int tid = threadIdx.x;
  const int ln  = tid & 63, w = tid >> 6;
  const int n16 = ln & 15, kgrp = ln >> 4;
  const int g   = w >> 1;
  const int jbase = (w & 1) * 32;

  // ---- weights -> register B-fragments (one-time) ----
  short8 wf[2][12];
  float biasv[2];
#pragma unroll
  for (int nt = 0; nt < 2; ++nt) {
    const int rglob = g * HH + bk * 64 + jbase + nt * 16 + n16;
    biasv[nt] = bih[rglob] + bhh[rglob];
#pragma unroll
    for (int kt = 0; kt < 12; ++kt) {
      const int k0 = kt * 32 + kgrp * 8;
      const float* src = (k0 < 256) ? (Whh + (size_t)rglob * HH + k0)
                                    : (Wih + (size_t)rglob * EE + (k0 - 256));
      const float4 v0 = ((const float4*)src)[0];
      const float4 v1 = ((const float4*)src)[1];
      short8 wv;
      wv[0]=(short)f2bf(v0.x); wv[1]=(short)f2bf(v0.y); wv[2]=(short)f2bf(v0.z); wv[3]=(short)f2bf(v0.w);
      wv[4]=(short)f2bf(v1.x); wv[5]=(short)f2bf(v1.y); wv[6]=(short)f2bf(v1.z); wv[7]=(short)f2bf(v1.w);
      wf[nt][kt] = wv;
    }
  }

  // ---- pointwise ownership: thread = (pb = tid>>3, jg = tid&7), j = bk*64 + jg*8 + u ----
  const int pb = tid >> 3, jg = tid & 7;
  float creg[8];
#pragma unroll
  for (int u = 0; u < 8; ++u) creg[u] = c0[(size_t)pb * HH + bk * 64 + jg * 8 + u];

  // ---- h(0) -> hx (full, from h0; no exchange needed at t=0) ----
#pragma unroll
  for (int i = 0; i < 4; ++i) {
    const int e = i * 512 + tid;          // 2048 entries: kc 0..31, b 0..63
    const int kc = e >> 6, b = e & 63;
    const float4 v0 = ((const float4*)(h0 + (size_t)b * HH + kc * 8))[0];
    const float4 v1 = ((const float4*)(h0 + (size_t)b * HH + kc * 8))[1];
    uint4 o;
    o.x = f2bf(v0.x) | ((unsigned)f2bf(v0.y) << 16);
    o.y = f2bf(v0.z) | ((unsigned)f2bf(v0.w) << 16);
    o.z = f2bf(v1.x) | ((unsigned)f2bf(v1.y) << 16);
    o.w = f2bf(v1.z) | ((unsigned)f2bf(v1.w) << 16);
    hx[kc * 64 + b] = o;
  }
  __syncthreads();

  for (int t = 0; t < TT; ++t) {
    // x entries for this step (independent of recurrence -> issue before poll)
    uint4 xe[2];
#pragma unroll
    for (int i = 0; i < 2; ++i) {
      const int e = i * 512 + tid;        // 1024 entries
      xe[i] = xembt[(size_t)(t * 16 + (e >> 6)) * 64 + (e & 63)];
    }

    if (t > 0) {
      if (tid < NB) {
        while (__hip_atomic_load(flags + tid, __ATOMIC_RELAXED, __HIP_MEMORY_SCOPE_AGENT) < (unsigned)t)
          __builtin_amdgcn_s_sleep(1);
      }
      __syncthreads();
      __builtin_amdgcn_fence(__ATOMIC_ACQUIRE, "agent");
      uint4 he[4];
#pragma unroll
      for (int i = 0; i < 4; ++i) {
        const int e = i * 512 + tid;
        he[i] = hex[(size_t)(t * 32 + (e >> 6)) * 64 + (e & 63)];
      }
#pragma unroll
      for (int i = 0; i < 4; ++i) {
        const int e = i * 512 + tid;
        hx[(e >> 6) * 64 + (e & 63)] = he[i];
      }
    }
#pragma unroll
    for (int i = 0; i < 2; ++i) {
      const int e = i * 512 + tid;
      hx[(32 + (e >> 6)) * 64 + (e & 63)] = xe[i];
    }
    __syncthreads();   // hx ready

    // ---- MFMA: 96 per wave ----
    f32x4 acc[4][2];
#pragma unroll
    for (int mt = 0; mt < 4; ++mt)
#pragma unroll
      for (int nt = 0; nt < 2; ++nt)
        acc[mt][nt] = (f32x4){biasv[nt], biasv[nt], biasv[nt], biasv[nt]};

#pragma unroll
    for (int kt = 0; kt < 12; ++kt) {
#pragma unroll
      for (int mt = 0; mt < 4; ++mt) {
        const short8 a = *(const short8*)&hx[(kt * 4 + kgrp) * 64 + mt * 16 + n16];
        acc[mt][0] = __builtin_amdgcn_mfma_f32_16x16x32_bf16(a, wf[0][kt], acc[mt][0], 0, 0, 0);
        acc[mt][1] = __builtin_amdgcn_mfma_f32_16x16x32_bf16(a, wf[1][kt], acc[mt][1], 0, 0, 0);
      }
    }

    // ---- gates -> LDS: row b, col rlocal = w*32 + nt*16 + n16 ----
#pragma unroll
    for (int mt = 0; mt < 4; ++mt)
#pragma unroll
      for (int nt = 0; nt < 2; ++nt)
#pragma unroll
        for (int r = 0; r < 4; ++r)
          gates[(mt * 16 + kgrp * 4 + r) * 260 + w * 32 + nt * 16 + n16] = acc[mt][nt][r];
    __syncthreads();

    // ---- pointwise: 8 j's for one b per thread ----
    {
      const float* gr = gates + pb * 260 + jg * 8;
      float hh[8];
#pragma unroll
      for (int u = 0; u < 8; ++u) {
        const float iv = gr[u], fv = gr[64 + u], gv = gr[128 + u], ov = gr[192 + u];
        const float cn = sigm(fv) * creg[u] + sigm(iv) * tanh_f(gv);
        creg[u] = cn;
        hh[u] = sigm(ov) * tanh_f(cn);
      }
      uint4 ph;
      ph.x = f2bf(hh[0]) | ((unsigned)f2bf(hh[1]) << 16);
      ph.y = f2bf(hh[2]) | ((unsigned)f2bf(hh[3]) << 16);
      ph.z = f2bf(hh[4]) | ((unsigned)f2bf(hh[5]) << 16);
      ph.w = f2bf(hh[6]) | ((unsigned)f2bf(hh[7]) << 16);
      hex[(size_t)((t + 1) * 32 + 8 * bk + jg) * 64 + pb] = ph;
    }
    asm volatile("s_waitcnt vmcnt(0)" ::: "memory");
    __syncthreads();
    if (tid == 0)
      __hip_atomic_store(flags + bk, (unsigned)(t + 1), __ATOMIC_RELEASE, __HIP_MEMORY_SCOPE_AGENT);
  }
}

// ------------------------------------------------------------------ attention (parallel over (b, t-quarter))
// reads h (bf16) from hex; writes hcat h-half AND ctx-half.
__launch_bounds__(256)
__global__ void attn_kernel(const float* __restrict__ enc, const int* __restrict__ lens,
                            const unsigned int* __restrict__ hexu,
                            unsigned short* __restrict__ hcat) {
  __shared__ __align__(16) float enc_s[SS * HH];
  __shared__ __align__(16) float h_s[HH];
  __shared__ float at_s[SS];

  const int b   = blockIdx.x >> 2;
  const int tq  = blockIdx.x & 3;
  const int tid = threadIdx.x;
  const int wv  = tid >> 6, ln = tid & 63;
  const int len = lens[b];
  unsigned int* hcatu = (unsigned int*)hcat;

  {
    const float4* src = (const float4*)(enc + (size_t)b * SS * HH);
    float4* dst = (float4*)enc_s;
    for (int i = tid; i < SS * HH / 4; i += 256) dst[i] = src[i];
  }

  for (int ti = 0; ti < TT / 4; ++ti) {
    const int t = tq * (TT / 4) + ti;
    __syncthreads();
    if (tid < 128) {
      const int kc = tid >> 2, q = tid & 3;
      const unsigned int v = hexu[((size_t)((t + 1) * 32 + kc) * 64 + b) * 4 + q];
      h_s[kc * 8 + q * 2]     = bf2f((unsigned short)(v & 0xffff));
      h_s[kc * 8 + q * 2 + 1] = bf2f((unsigned short)(v >> 16));
      hcatu[(size_t)(b * TT + t) * 256 + kc * 4 + q] = v;   // h-half of hcat
    }
    __syncthreads();

    const float4 hv = ((const float4*)h_s)[ln];
    for (int s = wv; s < SS; s += 4) {
      const float4 ev = ((const float4*)(enc_s + s * HH))[ln];
      float p = hv.x * ev.x + hv.y * ev.y + hv.z * ev.z + hv.w * ev.w;
      p = wsum(p);
      if (ln == 0) at_s[s] = p * 0.0625f;
    }
    __syncthreads();
    if (wv == 0) {
      const float v0 = (ln < len) ? at_s[ln] : -3.0e38f;
      const bool has1 = (ln < 8) && (64 + ln < len);
      const float v1 = has1 ? at_s[64 + ln] : -3.0e38f;
      const float m = wmax(fmaxf(v0, v1));
      const float e0 = (ln < len) ? __expf(v0 - m) : 0.f;
      const float e1 = has1 ? __expf(v1 - m) : 0.f;
      const float inv = 1.f / wsum(e0 + e1);
      at_s[ln] = e0 * inv;
      if (ln < 8) at_s[64 + ln] = e1 * inv;
    }
    __syncthreads();
    float acc = 0.f;
#pragma unroll 8
    for (int s = 0; s < SS; ++s) acc += at_s[s] * enc_s[s * HH + tid];
    hcat[(size_t)(b * TT + t) * KK + HH + tid] = f2bf(acc);
  }
}

// ------------------------------------------------------------------ vocab GEMM (validated)
__launch_bounds__(256)
__global__ void gemm_kernel(const unsigned short* __restrict__ A,
                            const unsigned short* __restrict__ Bw,
                            const float* __restrict__ blin,
                            float* __restrict__ out) {
  __shared__ __align__(16) unsigned short As[128 * 32];
  __shared__ __align__(16) unsigned short Bs[128 * 32];

  const int bid = blockIdx.x;
  const int mt = bid % 36;
  const int nt = bid / 36;
  const int m0 = mt * 128, n0 = nt * 128;
  const int tid = threadIdx.x;
  const int ln = tid & 63;
  const int w  = tid >> 6;
  const int wm = w >> 1, wn = w & 1;

  const char* Ab = (const char*)(A + (size_t)m0 * KK);
  const char* Bb = (const char*)(Bw + (size_t)n0 * KK);

  const int o0 = tid * 16;
  const int o1 = o0 + 4096;
  const int r0 = o0 >> 6, c0b = o0 & 63;
  const int r1 = o1 >> 6, c1b = o1 & 63;

  f32x4 acc[4][4] = {};

  float bs[4];
#pragma unroll
  for (int fn = 0; fn < 4; ++fn) bs[fn] = blin[n0 + wn * 64 + fn * 16 + (ln & 15)];

  for (int kt = 0; kt < 16; ++kt) {
    const int kb = kt * 64;
    g2l16(Ab + (size_t)r0 * (KK * 2) + kb + c0b, (char*)As + o0);
    g2l16(Ab + (size_t)r1 * (KK * 2) + kb + c1b, (char*)As + o1);
    g2l16(Bb + (size_t)r0 * (KK * 2) + kb + c0b, (char*)Bs + o0);
    g2l16(Bb + (size_t)r1 * (KK * 2) + kb + c1b, (char*)Bs + o1);
    __syncthreads();

    short8 af[4], bf[4];
#pragma unroll
    for (int f = 0; f < 4; ++f) {
      af[f] = *(const short8*)&As[(wm * 64 + f * 16 + (ln & 15)) * 32 + (ln >> 4) * 8];
      bf[f] = *(const short8*)&Bs[(wn * 64 + f * 16 + (ln & 15)) * 32 + (ln >> 4) * 8];
    }
#pragma unroll
    for (int fm = 0; fm < 4; ++fm)
#pragma unroll
      for (int fn = 0; fn < 4; ++fn)
        acc[fm][fn] = __builtin_amdgcn_mfma_f32_16x16x32_bf16(af[fm], bf[fn], acc[fm][fn], 0, 0, 0);
    __syncthreads();
  }

#pragma unroll
  for (int fm = 0; fm < 4; ++fm) {
    const int mrow = m0 + wm * 64 + fm * 16 + (ln >> 4) * 4;
#pragma unroll
    for (int fn = 0; fn < 4; ++fn) {
      const int n = n0 + wn * 64 + fn * 16 + (ln & 15);
      float* cp = out + (size_t)mrow * VV + n;
#pragma unroll
      for (int r = 0; r < 4; ++r) cp[(size_t)r * VV] = acc[fm][fn][r] + bs[fn];
    }
  }
}

// ------------------------------------------------------------------
extern "C" void kernel_launch(void* const* d_in, const int* in_sizes, int n_in,
                              void* d_out, int out_size, void* d_ws, size_t ws_size,
                              hipStream_t stream) {
  const int*   tok  = (const int*)  d_in[0];
  const float* enc  = (const float*)d_in[1];
  const int*   lens = (const int*)  d_in[2];
  const float* h0   = (const float*)d_in[3];
  const float* c0   = (const float*)d_in[4];
  const float* emb  = (const float*)d_in[5];
  const float* Wih  = (const float*)d_in[6];
  const float* Whh  = (const float*)d_in[7];
  const float* bih  = (const float*)d_in[8];
  const float* bhh  = (const float*)d_in[9];
  const float* Wlin = (const float*)d_in[10];
  const float* blin = (const float*)d_in[11];

  char* ws = (char*)d_ws;
  unsigned short* wlin16 = (unsigned short*)(ws);               // 32,768,000 B
  unsigned short* hcat   = (unsigned short*)(ws + 32768000);    //  4,718,592 B
  uint4*          xembt  = (uint4*)         (ws + 37486592);    //  1,179,648 B
  uint4*          hex    = (uint4*)         (ws + 38666240);    //  2,392,064 B
  unsigned int*   flags  = (unsigned int*)  (ws + 41058304);    //         64 B
  float* out = (float*)d_out;

  hipMemsetAsync(flags, 0, 64, stream);
  gather_kernel<<<(TT * 16 * 64 + 255) / 256, 256, 0, stream>>>(tok, emb, xembt);
  lstm_kernel<<<NB, 512, 0, stream>>>(h0, c0, Wih, Whh, bih, bhh, xembt, hex, flags);
  attn_kernel<<<BB * 4, 256, 0, stream>>>(enc, lens, (const unsigned int*)hex, hcat);
  cvt_kernel<<<2048, 256, 0, stream>>>(Wlin, wlin16, (VV * KK) / 4);
  gemm_kernel<<<36 * 250, 256, 0, stream>>>(hcat, wlin16, blin, out);
}

// Round 4
// 894.728 us; speedup vs baseline: 3.5112x; 1.0600x over previous
//
#include <hip/hip_runtime.h>

#define BB 64
#define TT 72
#define SS 72
#define EE 128
#define HH 256
#define VV 32000
#define KK 512
#define NB 4     // lstm worker blocks (j-partition), all on ONE XCD

using f32x4  = __attribute__((ext_vector_type(4))) float;
using short8 = __attribute__((ext_vector_type(8))) short;

__device__ __forceinline__ unsigned short f2bf(float f) {
  unsigned u = __float_as_uint(f);
  unsigned r = (u + 0x7fffu + ((u >> 16) & 1u)) >> 16;
  return (unsigned short)r;
}
__device__ __forceinline__ float bf2f(unsigned short b) {
  return __uint_as_float(((unsigned)b) << 16);
}
__device__ __forceinline__ float sigm(float x) { return 1.f / (1.f + __expf(-x)); }
__device__ __forceinline__ float tanh_f(float x) { return 1.f - 2.f / (__expf(2.f * x) + 1.f); }

__device__ __forceinline__ float wsum(float v) {
  v += __shfl_xor(v, 1, 64);  v += __shfl_xor(v, 2, 64);  v += __shfl_xor(v, 4, 64);
  v += __shfl_xor(v, 8, 64);  v += __shfl_xor(v, 16, 64); v += __shfl_xor(v, 32, 64);
  return v;
}
__device__ __forceinline__ float wmax(float v) {
  v = fmaxf(v, __shfl_xor(v, 1, 64));  v = fmaxf(v, __shfl_xor(v, 2, 64));
  v = fmaxf(v, __shfl_xor(v, 4, 64));  v = fmaxf(v, __shfl_xor(v, 8, 64));
  v = fmaxf(v, __shfl_xor(v, 16, 64)); v = fmaxf(v, __shfl_xor(v, 32, 64));
  return v;
}
__device__ __forceinline__ void g2l16(const void* g, void* l) {
  __builtin_amdgcn_global_load_lds((const __attribute__((address_space(1))) void*)g,
                                   (__attribute__((address_space(3))) void*)l, 16, 0, 0);
}

// ------------------------------------------------------------------ cvt W_lin fp32->bf16
__global__ void cvt_kernel(const float* __restrict__ src, unsigned short* __restrict__ dst,
                           int n4) {
  int i = blockIdx.x * blockDim.x + threadIdx.x;
  const int stride = gridDim.x * blockDim.x;
  for (; i < n4; i += stride) {
    float4 v = ((const float4*)src)[i];
    ushort4 o;
    o.x = f2bf(v.x); o.y = f2bf(v.y); o.z = f2bf(v.z); o.w = f2bf(v.w);
    ((ushort4*)dst)[i] = o;
  }
}

// ------------------------------------------------------------------ gather x = emb[tok] -> bf16
// layout: xembt[t][kcx 0..15][b 0..63] 16B entries
__global__ void gather_kernel(const int* __restrict__ tok, const float* __restrict__ emb,
                              uint4* __restrict__ xembt) {
  const int e = blockIdx.x * 256 + threadIdx.x;
  if (e >= TT * 16 * 64) return;
  const int b = e & 63, kcx = (e >> 6) & 15, t = e >> 10;
  const int tk = tok[b * TT + t];
  const float4* s = (const float4*)(emb + (size_t)tk * EE + kcx * 8);
  const float4 v0 = s[0], v1 = s[1];
  uint4 o;
  o.x = f2bf(v0.x) | ((unsigned)f2bf(v0.y) << 16);
  o.y = f2bf(v0.z) | ((unsigned)f2bf(v0.w) << 16);
  o.z = f2bf(v1.x) | ((unsigned)f2bf(v1.y) << 16);
  o.w = f2bf(v1.z) | ((unsigned)f2bf(v1.w) << 16);
  xembt[e] = o;
}

// ------------------------------------------------------------------ lstm (sequential)
// 64 candidate blocks; 4 workers elected on ONE XCD (shared L2). Slot bk owns
// j in [64bk, 64bk+64). Weight B-frags in VGPRs. h exchange through the shared
// L2 via sc0 (agent-relaxed) loads/stores; no release/acquire fences at all.
__launch_bounds__(512)
__global__ void lstm_kernel(const float* __restrict__ h0, const float* __restrict__ c0,
                            const float* __restrict__ Wih, const float* __restrict__ Whh,
                            const float* __restrict__ bih, const float* __restrict__ bhh,
                            const uint4* __restrict__ xembt,
                            uint4* __restrict__ hex,          // [73][32][64] 16B entries
                            unsigned int* __restrict__ flags, // [0..3]=step flags
                            unsigned int* __restrict__ elect) // [0..7]=arrivals, [8]=winner
{
  __shared__ __align__(16) uint4 hx[48 * 64];     // 49152 B: kc 0..31 = h, 32..47 = x
  __shared__ float gates[64 * 260];               // 66560 B
  __shared__ int s_slot;

  const int tid = threadIdx.x;

  // ---- election: first XCD to assemble 4 blocks wins ----
  if (tid == 0) {
    unsigned xcd;
    asm volatile("s_getreg_b32 %0, hwreg(20, 0, 8)" : "=s"(xcd));  // HW_REG_XCC_ID
    xcd &= 7;
    int slot = -1;
    const unsigned my = __hip_atomic_fetch_add(elect + xcd, 1u,
                          __ATOMIC_RELAXED, __HIP_MEMORY_SCOPE_AGENT);
    if (my < NB) {
      if (my == NB - 1) {
        unsigned exp = 0;
        __hip_atomic_compare_exchange_strong(elect + 8, &exp, xcd + 1,
            __ATOMIC_RELAXED, __ATOMIC_RELAXED, __HIP_MEMORY_SCOPE_AGENT);
      }
      unsigned wv;
      while ((wv = __hip_atomic_load(elect + 8, __ATOMIC_RELAXED,
                                     __HIP_MEMORY_SCOPE_AGENT)) == 0)
        __builtin_amdgcn_s_sleep(1);
      if (wv == xcd + 1) slot = (int)my;
    }
    s_slot = slot;
  }
  __syncthreads();
  const int bk = s_slot;
  if (bk < 0) return;

  const int ln  = tid & 63, w = tid >> 6;
  const int n16 = ln & 15, kgrp = ln >> 4;
  const int g   = w >> 1;
  const int jbase = (w & 1) * 32;
  unsigned long long* hexq = (unsigned long long*)hex;

  // ---- weights -> register B-fragments (one-time) ----
  short8 wf[2][12];
  float biasv[2];
#pragma unroll
  for (int nt = 0; nt < 2; ++nt) {
    const int rglob = g * HH + bk * 64 + jbase + nt * 16 + n16;
    biasv[nt] = bih[rglob] + bhh[rglob];
#pragma unroll
    for (int kt = 0; kt < 12; ++kt) {
      const int k0 = kt * 32 + kgrp * 8;
      const float* src = (k0 < 256) ? (Whh + (size_t)rglob * HH + k0)
                                    : (Wih + (size_t)rglob * EE + (k0 - 256));
      const float4 v0 = ((const float4*)src)[0];
      const float4 v1 = ((const float4*)src)[1];
      short8 wv;
      wv[0]=(short)f2bf(v0.x); wv[1]=(short)f2bf(v0.y); wv[2]=(short)f2bf(v0.z); wv[3]=(short)f2bf(v0.w);
      wv[4]=(short)f2bf(v1.x); wv[5]=(short)f2bf(v1.y); wv[6]=(short)f2bf(v1.z); wv[7]=(short)f2bf(v1.w);
      wf[nt][kt] = wv;
    }
  }

  // ---- pointwise ownership ----
  const int pb = tid >> 3, jg = tid & 7;
  float creg[8];
#pragma unroll
  for (int u = 0; u < 8; ++u) creg[u] = c0[(size_t)pb * HH + bk * 64 + jg * 8 + u];

  // ---- h(0) -> hx (full, from h0) ----
#pragma unroll
  for (int i = 0; i < 4; ++i) {
    const int e = i * 512 + tid;
    const int kc = e >> 6, b = e & 63;
    const float4 v0 = ((const float4*)(h0 + (size_t)b * HH + kc * 8))[0];
    const float4 v1 = ((const float4*)(h0 + (size_t)b * HH + kc * 8))[1];
    uint4 o;
    o.x = f2bf(v0.x) | ((unsigned)f2bf(v0.y) << 16);
    o.y = f2bf(v0.z) | ((unsigned)f2bf(v0.w) << 16);
    o.z = f2bf(v1.x) | ((unsigned)f2bf(v1.y) << 16);
    o.w = f2bf(v1.z) | ((unsigned)f2bf(v1.w) << 16);
    hx[kc * 64 + b] = o;
  }
  __syncthreads();

  for (int t = 0; t < TT; ++t) {
    // x entries (recurrence-independent: issue before poll)
    uint4 xe[2];
#pragma unroll
    for (int i = 0; i < 2; ++i) {
      const int e = i * 512 + tid;
      xe[i] = xembt[(size_t)(t * 16 + (e >> 6)) * 64 + (e & 63)];
    }

    if (t > 0) {
      if (tid < NB) {
        while (__hip_atomic_load(flags + tid, __ATOMIC_RELAXED,
                                 __HIP_MEMORY_SCOPE_AGENT) < (unsigned)t)
          __builtin_amdgcn_s_sleep(1);
      }
      __syncthreads();
      // foreign h slices (24 kc), sc0 loads from the shared L2
      unsigned long long hq[3][2];
#pragma unroll
      for (int i = 0; i < 3; ++i) {
        const int e = i * 512 + tid;
        const int kcp = e >> 6;
        const int kc = kcp + (kcp >= 8 * bk ? 8 : 0);
        const unsigned long long* src = hexq + ((size_t)(t * 32 + kc) * 64 + (e & 63)) * 2;
        hq[i][0] = __hip_atomic_load(src,     __ATOMIC_RELAXED, __HIP_MEMORY_SCOPE_AGENT);
        hq[i][1] = __hip_atomic_load(src + 1, __ATOMIC_RELAXED, __HIP_MEMORY_SCOPE_AGENT);
      }
#pragma unroll
      for (int i = 0; i < 3; ++i) {
        const int e = i * 512 + tid;
        const int kcp = e >> 6;
        const int kc = kcp + (kcp >= 8 * bk ? 8 : 0);
        unsigned long long* d = (unsigned long long*)&hx[kc * 64 + (e & 63)];
        d[0] = hq[i][0]; d[1] = hq[i][1];
      }
    }
#pragma unroll
    for (int i = 0; i < 2; ++i) {
      const int e = i * 512 + tid;
      hx[(32 + (e >> 6)) * 64 + (e & 63)] = xe[i];
    }
    __syncthreads();   // hx ready

    // ---- MFMA: 96 per wave ----
    f32x4 acc[4][2];
#pragma unroll
    for (int mt = 0; mt < 4; ++mt)
#pragma unroll
      for (int nt = 0; nt < 2; ++nt)
        acc[mt][nt] = (f32x4){biasv[nt], biasv[nt], biasv[nt], biasv[nt]};

#pragma unroll
    for (int kt = 0; kt < 12; ++kt) {
#pragma unroll
      for (int mt = 0; mt < 4; ++mt) {
        const short8 a = *(const short8*)&hx[(kt * 4 + kgrp) * 64 + mt * 16 + n16];
        acc[mt][0] = __builtin_amdgcn_mfma_f32_16x16x32_bf16(a, wf[0][kt], acc[mt][0], 0, 0, 0);
        acc[mt][1] = __builtin_amdgcn_mfma_f32_16x16x32_bf16(a, wf[1][kt], acc[mt][1], 0, 0, 0);
      }
    }

    // ---- gates -> LDS ----
#pragma unroll
    for (int mt = 0; mt < 4; ++mt)
#pragma unroll
      for (int nt = 0; nt < 2; ++nt)
#pragma unroll
        for (int r = 0; r < 4; ++r)
          gates[(mt * 16 + kgrp * 4 + r) * 260 + w * 32 + nt * 16 + n16] = acc[mt][nt][r];
    __syncthreads();

    // ---- pointwise; own h-slice -> L2 (sc0) AND directly into LDS ----
    {
      const float* gr = gates + pb * 260 + jg * 8;
      float hh[8];
#pragma unroll
      for (int u = 0; u < 8; ++u) {
        const float iv = gr[u], fv = gr[64 + u], gv = gr[128 + u], ov = gr[192 + u];
        const float cn = sigm(fv) * creg[u] + sigm(iv) * tanh_f(gv);
        creg[u] = cn;
        hh[u] = sigm(ov) * tanh_f(cn);
      }
      uint4 ph;
      ph.x = f2bf(hh[0]) | ((unsigned)f2bf(hh[1]) << 16);
      ph.y = f2bf(hh[2]) | ((unsigned)f2bf(hh[3]) << 16);
      ph.z = f2bf(hh[4]) | ((unsigned)f2bf(hh[5]) << 16);
      ph.w = f2bf(hh[6]) | ((unsigned)f2bf(hh[7]) << 16);
      unsigned long long* dst = hexq + ((size_t)((t + 1) * 32 + 8 * bk + jg) * 64 + pb) * 2;
      __hip_atomic_store(dst,     ((unsigned long long)ph.y << 32) | ph.x,
                         __ATOMIC_RELAXED, __HIP_MEMORY_SCOPE_AGENT);
      __hip_atomic_store(dst + 1, ((unsigned long long)ph.w << 32) | ph.z,
                         __ATOMIC_RELAXED, __HIP_MEMORY_SCOPE_AGENT);
      hx[(8 * bk + jg) * 64 + pb] = ph;   // own slice for next step (skip reload)
    }
    asm volatile("s_waitcnt vmcnt(0)" ::: "memory");
    __syncthreads();
    if (tid == 0)
      __hip_atomic_store(flags + bk, (unsigned)(t + 1),
                         __ATOMIC_RELAXED, __HIP_MEMORY_SCOPE_AGENT);
  }
}

// ------------------------------------------------------------------ attention (parallel over (b, t-quarter))
__launch_bounds__(256)
__global__ void attn_kernel(const float* __restrict__ enc, const int* __restrict__ lens,
                            const unsigned int* __restrict__ hexu,
                            unsigned short* __restrict__ hcat) {
  __shared__ __align__(16) float enc_s[SS * HH];
  __shared__ __align__(16) float h_s[HH];
  __shared__ float at_s[SS];

  const int b   = blockIdx.x >> 2;
  const int tq  = blockIdx.x & 3;
  const int tid = threadIdx.x;
  const int wv  = tid >> 6, ln = tid & 63;
  const int len = lens[b];
  unsigned int* hcatu = (unsigned int*)hcat;

  {
    const float4* src = (const float4*)(enc + (size_t)b * SS * HH);
    float4* dst = (float4*)enc_s;
    for (int i = tid; i < SS * HH / 4; i += 256) dst[i] = src[i];
  }

  for (int ti = 0; ti < TT / 4; ++ti) {
    const int t = tq * (TT / 4) + ti;
    __syncthreads();
    if (tid < 128) {
      const int kc = tid >> 2, q = tid & 3;
      const unsigned int v = hexu[((size_t)((t + 1) * 32 + kc) * 64 + b) * 4 + q];
      h_s[kc * 8 + q * 2]     = bf2f((unsigned short)(v & 0xffff));
      h_s[kc * 8 + q * 2 + 1] = bf2f((unsigned short)(v >> 16));
      hcatu[(size_t)(b * TT + t) * 256 + kc * 4 + q] = v;
    }
    __syncthreads();

    const float4 hv = ((const float4*)h_s)[ln];
    for (int s = wv; s < SS; s += 4) {
      const float4 ev = ((const float4*)(enc_s + s * HH))[ln];
      float p = hv.x * ev.x + hv.y * ev.y + hv.z * ev.z + hv.w * ev.w;
      p = wsum(p);
      if (ln == 0) at_s[s] = p * 0.0625f;
    }
    __syncthreads();
    if (wv == 0) {
      const float v0 = (ln < len) ? at_s[ln] : -3.0e38f;
      const bool has1 = (ln < 8) && (64 + ln < len);
      const float v1 = has1 ? at_s[64 + ln] : -3.0e38f;
      const float m = wmax(fmaxf(v0, v1));
      const float e0 = (ln < len) ? __expf(v0 - m) : 0.f;
      const float e1 = has1 ? __expf(v1 - m) : 0.f;
      const float inv = 1.f / wsum(e0 + e1);
      at_s[ln] = e0 * inv;
      if (ln < 8) at_s[64 + ln] = e1 * inv;
    }
    __syncthreads();
    float acc = 0.f;
#pragma unroll 8
    for (int s = 0; s < SS; ++s) acc += at_s[s] * enc_s[s * HH + tid];
    hcat[(size_t)(b * TT + t) * KK + HH + tid] = f2bf(acc);
  }
}

// ------------------------------------------------------------------ vocab GEMM (validated)
__launch_bounds__(256)
__global__ void gemm_kernel(const unsigned short* __restrict__ A,
                            const unsigned short* __restrict__ Bw,
                            const float* __restrict__ blin,
                            float* __restrict__ out) {
  __shared__ __align__(16) unsigned short As[128 * 32];
  __shared__ __align__(16) unsigned short Bs[128 * 32];

  const int bid = blockIdx.x;
  const int mt = bid % 36;
  const int nt = bid / 36;
  const int m0 = mt * 128, n0 = nt * 128;
  const int tid = threadIdx.x;
  const int ln = tid & 63;
  const int w  = tid >> 6;
  const int wm = w >> 1, wn = w & 1;

  const char* Ab = (const char*)(A + (size_t)m0 * KK);
  const char* Bb = (const char*)(Bw + (size_t)n0 * KK);

  const int o0 = tid * 16;
  const int o1 = o0 + 4096;
  const int r0 = o0 >> 6, c0b = o0 & 63;
  const int r1 = o1 >> 6, c1b = o1 & 63;

  f32x4 acc[4][4] = {};

  float bs[4];
#pragma unroll
  for (int fn = 0; fn < 4; ++fn) bs[fn] = blin[n0 + wn * 64 + fn * 16 + (ln & 15)];

  for (int kt = 0; kt < 16; ++kt) {
    const int kb = kt * 64;
    g2l16(Ab + (size_t)r0 * (KK * 2) + kb + c0b, (char*)As + o0);
    g2l16(Ab + (size_t)r1 * (KK * 2) + kb + c1b, (char*)As + o1);
    g2l16(Bb + (size_t)r0 * (KK * 2) + kb + c0b, (char*)Bs + o0);
    g2l16(Bb + (size_t)r1 * (KK * 2) + kb + c1b, (char*)Bs + o1);
    __syncthreads();

    short8 af[4], bf[4];
#pragma unroll
    for (int f = 0; f < 4; ++f) {
      af[f] = *(const short8*)&As[(wm * 64 + f * 16 + (ln & 15)) * 32 + (ln >> 4) * 8];
      bf[f] = *(const short8*)&Bs[(wn * 64 + f * 16 + (ln & 15)) * 32 + (ln >> 4) * 8];
    }
#pragma unroll
    for (int fm = 0; fm < 4; ++fm)
#pragma unroll
      for (int fn = 0; fn < 4; ++fn)
        acc[fm][fn] = __builtin_amdgcn_mfma_f32_16x16x32_bf16(af[fm], bf[fn], acc[fm][fn], 0, 0, 0);
    __syncthreads();
  }

#pragma unroll
  for (int fm = 0; fm < 4; ++fm) {
    const int mrow = m0 + wm * 64 + fm * 16 + (ln >> 4) * 4;
#pragma unroll
    for (int fn = 0; fn < 4; ++fn) {
      const int n = n0 + wn * 64 + fn * 16 + (ln & 15);
      float* cp = out + (size_t)mrow * VV + n;
#pragma unroll
      for (int r = 0; r < 4; ++r) cp[(size_t)r * VV] = acc[fm][fn][r] + bs[fn];
    }
  }
}

// ------------------------------------------------------------------
extern "C" void kernel_launch(void* const* d_in, const int* in_sizes, int n_in,
                              void* d_out, int out_size, void* d_ws, size_t ws_size,
                              hipStream_t stream) {
  const int*   tok  = (const int*)  d_in[0];
  const float* enc  = (const float*)d_in[1];
  const int*   lens = (const int*)  d_in[2];
  const float* h0   = (const float*)d_in[3];
  const float* c0   = (const float*)d_in[4];
  const float* emb  = (const float*)d_in[5];
  const float* Wih  = (const float*)d_in[6];
  const float* Whh  = (const float*)d_in[7];
  const float* bih  = (const float*)d_in[8];
  const float* bhh  = (const float*)d_in[9];
  const float* Wlin = (const float*)d_in[10];
  const float* blin = (const float*)d_in[11];

  char* ws = (char*)d_ws;
  unsigned short* wlin16 = (unsigned short*)(ws);               // 32,768,000 B
  unsigned short* hcat   = (unsigned short*)(ws + 32768000);    //  4,718,592 B
  uint4*          xembt  = (uint4*)         (ws + 37486592);    //  1,179,648 B
  uint4*          hex    = (uint4*)         (ws + 38666240);    //  2,392,064 B
  unsigned int*   flags  = (unsigned int*)  (ws + 41058304);    //  16 B
  unsigned int*   elect  = (unsigned int*)  (ws + 41058320);    //  36 B
  float* out = (float*)d_out;

  hipMemsetAsync(flags, 0, 64, stream);
  gather_kernel<<<(TT * 16 * 64 + 255) / 256, 256, 0, stream>>>(tok, emb, xembt);
  lstm_kernel<<<64, 512, 0, stream>>>(h0, c0, Wih, Whh, bih, bhh, xembt, hex, flags, elect);
  attn_kernel<<<BB * 4, 256, 0, stream>>>(enc, lens, (const unsigned int*)hex, hcat);
  cvt_kernel<<<2048, 256, 0, stream>>>(Wlin, wlin16, (VV * KK) / 4);
  gemm_kernel<<<36 * 250, 256, 0, stream>>>(hcat, wlin16, blin, out);
}

// Round 5
// 824.009 us; speedup vs baseline: 3.8125x; 1.0858x over previous
//
#include <hip/hip_runtime.h>

#define BB 64
#define TT 72
#define SS 72
#define EE 128
#define HH 256
#define VV 32000
#define KK 512
#define NB 4     // lstm worker blocks (j-partition), all on ONE XCD

using f32x4  = __attribute__((ext_vector_type(4))) float;
using short8 = __attribute__((ext_vector_type(8))) short;

__device__ __forceinline__ unsigned short f2bf(float f) {
  unsigned u = __float_as_uint(f);
  unsigned r = (u + 0x7fffu + ((u >> 16) & 1u)) >> 16;
  return (unsigned short)r;
}
__device__ __forceinline__ float bf2f(unsigned short b) {
  return __uint_as_float(((unsigned)b) << 16);
}
__device__ __forceinline__ float sigm(float x) { return 1.f / (1.f + __expf(-x)); }
__device__ __forceinline__ float tanh_f(float x) { return 1.f - 2.f / (__expf(2.f * x) + 1.f); }

__device__ __forceinline__ float wsum(float v) {
  v += __shfl_xor(v, 1, 64);  v += __shfl_xor(v, 2, 64);  v += __shfl_xor(v, 4, 64);
  v += __shfl_xor(v, 8, 64);  v += __shfl_xor(v, 16, 64); v += __shfl_xor(v, 32, 64);
  return v;
}
__device__ __forceinline__ float wmax(float v) {
  v = fmaxf(v, __shfl_xor(v, 1, 64));  v = fmaxf(v, __shfl_xor(v, 2, 64));
  v = fmaxf(v, __shfl_xor(v, 4, 64));  v = fmaxf(v, __shfl_xor(v, 8, 64));
  v = fmaxf(v, __shfl_xor(v, 16, 64)); v = fmaxf(v, __shfl_xor(v, 32, 64));
  return v;
}
__device__ __forceinline__ void g2l16(const void* g, void* l) {
  __builtin_amdgcn_global_load_lds((const __attribute__((address_space(1))) void*)g,
                                   (__attribute__((address_space(3))) void*)l, 16, 0, 0);
}

// ------------------------------------------------------------------ cvt W_lin fp32->bf16
__global__ void cvt_kernel(const float* __restrict__ src, unsigned short* __restrict__ dst,
                           int n4) {
  int i = blockIdx.x * blockDim.x + threadIdx.x;
  const int stride = gridDim.x * blockDim.x;
  for (; i < n4; i += stride) {
    float4 v = ((const float4*)src)[i];
    ushort4 o;
    o.x = f2bf(v.x); o.y = f2bf(v.y); o.z = f2bf(v.z); o.w = f2bf(v.w);
    ((ushort4*)dst)[i] = o;
  }
}

// ------------------------------------------------------------------ gather x = emb[tok] -> bf16
// layout: xembt[t][kcx 0..15][b 0..63] 16B entries (8 consecutive k for one b)
__global__ void gather_kernel(const int* __restrict__ tok, const float* __restrict__ emb,
                              uint4* __restrict__ xembt) {
  const int e = blockIdx.x * 256 + threadIdx.x;
  if (e >= TT * 16 * 64) return;
  const int b = e & 63, kcx = (e >> 6) & 15, t = e >> 10;
  const int tk = tok[b * TT + t];
  const float4* s = (const float4*)(emb + (size_t)tk * EE + kcx * 8);
  const float4 v0 = s[0], v1 = s[1];
  uint4 o;
  o.x = f2bf(v0.x) | ((unsigned)f2bf(v0.y) << 16);
  o.y = f2bf(v0.z) | ((unsigned)f2bf(v0.w) << 16);
  o.z = f2bf(v1.x) | ((unsigned)f2bf(v1.y) << 16);
  o.w = f2bf(v1.z) | ((unsigned)f2bf(v1.w) << 16);
  xembt[e] = o;
}

// ------------------------------------------------------------------ lstm (sequential)
// 64 candidate blocks; 4 workers elected on ONE XCD. Slot bk owns j in
// [64bk,64bk+64). gates^T = W @ [h;x] via mfma(a=W-frag, b=hx-frag): each lane
// holds all 4 gates of its (batch,j) cells in acc[g][mt][r] -> pointwise fully
// in registers. h-part weights (K=256) in VGPRs (128), x-part (K=128) in LDS
// fragment layout. Wave w = (wj = w>>1 in 0..3: 16-j tile; wb = w&1: 32-batch half).
__launch_bounds__(512, 2)
__global__ void lstm_kernel(const float* __restrict__ h0, const float* __restrict__ c0,
                            const float* __restrict__ Wih, const float* __restrict__ Whh,
                            const float* __restrict__ bih, const float* __restrict__ bhh,
                            const uint4* __restrict__ xembt,
                            uint4* __restrict__ hex,          // [73][32 kc][64 b] 16B entries
                            unsigned int* __restrict__ flags,
                            unsigned int* __restrict__ elect) {
  __shared__ __align__(16) uint4 hx[48 * 64];   // 49152 B: kc 0..31 = h, 32..47 = x
  __shared__ __align__(16) uint4 xw[4096];      // 65536 B: x-part weight fragments
  __shared__ int s_slot;

  const int tid = threadIdx.x;

  // ---- election: first XCD to assemble 4 blocks wins ----
  if (tid == 0) {
    unsigned xcd;
    asm volatile("s_getreg_b32 %0, hwreg(20, 0, 8)" : "=s"(xcd));  // HW_REG_XCC_ID
    xcd &= 7;
    int slot = -1;
    const unsigned my = __hip_atomic_fetch_add(elect + xcd, 1u,
                          __ATOMIC_RELAXED, __HIP_MEMORY_SCOPE_AGENT);
    if (my < NB) {
      if (my == NB - 1) {
        unsigned exp = 0;
        __hip_atomic_compare_exchange_strong(elect + 8, &exp, xcd + 1,
            __ATOMIC_RELAXED, __ATOMIC_RELAXED, __HIP_MEMORY_SCOPE_AGENT);
      }
      unsigned wv;
      while ((wv = __hip_atomic_load(elect + 8, __ATOMIC_RELAXED,
                                     __HIP_MEMORY_SCOPE_AGENT)) == 0)
        __builtin_amdgcn_s_sleep(1);
      if (wv == xcd + 1) slot = (int)my;
    }
    s_slot = slot;
  }
  __syncthreads();
  const int bk = s_slot;
  if (bk < 0) return;

  const int ln  = tid & 63, w = tid >> 6;
  const int n16 = ln & 15, kgrp = ln >> 4;
  const int wj  = w >> 1;       // 16-j tile within block's 64 j
  const int wb  = w & 1;        // 32-batch half
  unsigned long long* hexq = (unsigned long long*)hex;

  // ---- h-part weights -> registers: wf[gate][kt], row = lane n16 of the tile ----
  short8 wf[4][8];
  f32x4 biasf[4];
  {
    const int jrow = bk * 64 + wj * 16;    // block+wave j base
#pragma unroll
    for (int g = 0; g < 4; ++g) {
      const int row = g * HH + jrow + n16;
#pragma unroll
      for (int kt = 0; kt < 8; ++kt) {
        const float* src = Whh + (size_t)row * HH + kt * 32 + kgrp * 8;
        const float4 v0 = ((const float4*)src)[0];
        const float4 v1 = ((const float4*)src)[1];
        short8 wv;
        wv[0]=(short)f2bf(v0.x); wv[1]=(short)f2bf(v0.y); wv[2]=(short)f2bf(v0.z); wv[3]=(short)f2bf(v0.w);
        wv[4]=(short)f2bf(v1.x); wv[5]=(short)f2bf(v1.y); wv[6]=(short)f2bf(v1.z); wv[7]=(short)f2bf(v1.w);
        wf[g][kt] = wv;
      }
      const int r4 = g * HH + jrow + kgrp * 4;   // bias rows for acc r=0..3
      const float4 bi = *(const float4*)(bih + r4);
      const float4 bh = *(const float4*)(bhh + r4);
      biasf[g] = (f32x4){bi.x + bh.x, bi.y + bh.y, bi.z + bh.z, bi.w + bh.w};
    }
  }

  // ---- x-part weights -> LDS fragments: xw[g][kti][wj][kgrp][n16] ----
#pragma unroll
  for (int i = 0; i < 8; ++i) {
    const int e = i * 512 + tid;          // 4096 entries
    const int en = e & 15, ek = (e >> 4) & 3, ewj = (e >> 6) & 3,
              ekt = (e >> 8) & 3, eg = e >> 10;
    const int row = eg * HH + bk * 64 + ewj * 16 + en;
    const float* src = Wih + (size_t)row * EE + ekt * 32 + ek * 8;
    const float4 v0 = ((const float4*)src)[0];
    const float4 v1 = ((const float4*)src)[1];
    uint4 o;
    o.x = f2bf(v0.x) | ((unsigned)f2bf(v0.y) << 16);
    o.y = f2bf(v0.z) | ((unsigned)f2bf(v0.w) << 16);
    o.z = f2bf(v1.x) | ((unsigned)f2bf(v1.y) << 16);
    o.w = f2bf(v1.z) | ((unsigned)f2bf(v1.w) << 16);
    xw[e] = o;
  }

  // ---- c-state: lane owns (batch = (2wb+mt)*16+n16, j = bk*64+wj*16+kgrp*4+r) ----
  float creg[2][4];
#pragma unroll
  for (int mt = 0; mt < 2; ++mt)
#pragma unroll
    for (int r = 0; r < 4; ++r)
      creg[mt][r] = c0[(size_t)((wb * 2 + mt) * 16 + n16) * HH + bk * 64 + wj * 16 + kgrp * 4 + r];

  // ---- h(0) -> hx from h0 ----
#pragma unroll
  for (int i = 0; i < 4; ++i) {
    const int e = i * 512 + tid;          // 2048 entries: kc 0..31, b 0..63
    const int kc = e >> 6, b = e & 63;
    const float4 v0 = ((const float4*)(h0 + (size_t)b * HH + kc * 8))[0];
    const float4 v1 = ((const float4*)(h0 + (size_t)b * HH + kc * 8))[1];
    uint4 o;
    o.x = f2bf(v0.x) | ((unsigned)f2bf(v0.y) << 16);
    o.y = f2bf(v0.z) | ((unsigned)f2bf(v0.w) << 16);
    o.z = f2bf(v1.x) | ((unsigned)f2bf(v1.y) << 16);
    o.w = f2bf(v1.z) | ((unsigned)f2bf(v1.w) << 16);
    hx[kc * 64 + b] = o;
  }
  __syncthreads();

  const int kcq  = bk * 8 + wj * 2 + (kgrp >> 1);   // hex kc for this lane's j-quad
  const int half = kgrp & 1;

  for (int t = 0; t < TT; ++t) {
    // x panel for this step via global_load_lds (recurrence-independent)
#pragma unroll
    for (int i = 0; i < 2; ++i) {
      const int e = (i * 8 + w) * 64 + ln;          // 1024 entries
      g2l16(xembt + (size_t)t * 1024 + e, (char*)&hx[32 * 64] + e * 16);
    }

    if (t > 0) {
      if (tid < NB) {
        while (__hip_atomic_load(flags + tid, __ATOMIC_RELAXED,
                                 __HIP_MEMORY_SCOPE_AGENT) < (unsigned)t)
          __builtin_amdgcn_s_sleep(1);
      }
      __syncthreads();
      // h panel from hex (same-XCD L2); values are replay-invariant so any
      // stale L1 line holds identical bytes.
#pragma unroll
      for (int i = 0; i < 4; ++i) {
        const int e = (i * 8 + w) * 64 + ln;        // 2048 entries
        g2l16(hex + (size_t)t * 2048 + e, (char*)hx + e * 16);
      }
    }
    __syncthreads();   // drains vmcnt(0): hx fully staged

    // ---- MFMA: acc[g][mt] = bias + W @ [h;x], lane holds 4 gates of its cells ----
    f32x4 acc[4][2];
#pragma unroll
    for (int g = 0; g < 4; ++g)
#pragma unroll
      for (int mt = 0; mt < 2; ++mt)
        acc[g][mt] = biasf[g];

#pragma unroll
    for (int kt = 0; kt < 8; ++kt) {
#pragma unroll
      for (int mt = 0; mt < 2; ++mt) {
        const short8 b = *(const short8*)&hx[(kt * 4 + kgrp) * 64 + (wb * 2 + mt) * 16 + n16];
        acc[0][mt] = __builtin_amdgcn_mfma_f32_16x16x32_bf16(wf[0][kt], b, acc[0][mt], 0, 0, 0);
        acc[1][mt] = __builtin_amdgcn_mfma_f32_16x16x32_bf16(wf[1][kt], b, acc[1][mt], 0, 0, 0);
        acc[2][mt] = __builtin_amdgcn_mfma_f32_16x16x32_bf16(wf[2][kt], b, acc[2][mt], 0, 0, 0);
        acc[3][mt] = __builtin_amdgcn_mfma_f32_16x16x32_bf16(wf[3][kt], b, acc[3][mt], 0, 0, 0);
      }
    }
#pragma unroll
    for (int kti = 0; kti < 4; ++kti) {
      short8 wx[4];
#pragma unroll
      for (int g = 0; g < 4; ++g)
        wx[g] = *(const short8*)&xw[(((g * 4 + kti) * 4 + wj) * 4 + kgrp) * 16 + n16];
#pragma unroll
      for (int mt = 0; mt < 2; ++mt) {
        const short8 b = *(const short8*)&hx[(32 + kti * 4 + kgrp) * 64 + (wb * 2 + mt) * 16 + n16];
#pragma unroll
        for (int g = 0; g < 4; ++g)
          acc[g][mt] = __builtin_amdgcn_mfma_f32_16x16x32_bf16(wx[g], b, acc[g][mt], 0, 0, 0);
      }
    }

    // ---- pointwise LSTM cell fully in registers ----
#pragma unroll
    for (int mt = 0; mt < 2; ++mt) {
      unsigned long long pk = 0;
#pragma unroll
      for (int r = 0; r < 4; ++r) {
        const float iv = acc[0][mt][r], fv = acc[1][mt][r],
                    gv = acc[2][mt][r], ov = acc[3][mt][r];
        const float cn = sigm(fv) * creg[mt][r] + sigm(iv) * tanh_f(gv);
        creg[mt][r] = cn;
        const float hv = sigm(ov) * tanh_f(cn);
        pk |= (unsigned long long)f2bf(hv) << (16 * r);
      }
      const int batch = (wb * 2 + mt) * 16 + n16;
      __hip_atomic_store(hexq + ((size_t)((t + 1) * 32 + kcq) * 64 + batch) * 2 + half,
                         pk, __ATOMIC_RELAXED, __HIP_MEMORY_SCOPE_AGENT);
    }
    asm volatile("s_waitcnt vmcnt(0)" ::: "memory");
    __syncthreads();
    if (tid == 0)
      __hip_atomic_store(flags + bk, (unsigned)(t + 1),
                         __ATOMIC_RELAXED, __HIP_MEMORY_SCOPE_AGENT);
  }
}

// ------------------------------------------------------------------ attention (parallel over (b, t-quarter))
__launch_bounds__(256)
__global__ void attn_kernel(const float* __restrict__ enc, const int* __restrict__ lens,
                            const unsigned int* __restrict__ hexu,
                            unsigned short* __restrict__ hcat) {
  __shared__ __align__(16) float enc_s[SS * HH];
  __shared__ __align__(16) float h_s[HH];
  __shared__ float at_s[SS];

  const int b   = blockIdx.x >> 2;
  const int tq  = blockIdx.x & 3;
  const int tid = threadIdx.x;
  const int wv  = tid >> 6, ln = tid & 63;
  const int len = lens[b];
  unsigned int* hcatu = (unsigned int*)hcat;

  {
    const float4* src = (const float4*)(enc + (size_t)b * SS * HH);
    float4* dst = (float4*)enc_s;
    for (int i = tid; i < SS * HH / 4; i += 256) dst[i] = src[i];
  }

  for (int ti = 0; ti < TT / 4; ++ti) {
    const int t = tq * (TT / 4) + ti;
    __syncthreads();
    if (tid < 128) {
      const int kc = tid >> 2, q = tid & 3;
      const unsigned int v = hexu[((size_t)((t + 1) * 32 + kc) * 64 + b) * 4 + q];
      h_s[kc * 8 + q * 2]     = bf2f((unsigned short)(v & 0xffff));
      h_s[kc * 8 + q * 2 + 1] = bf2f((unsigned short)(v >> 16));
      hcatu[(size_t)(b * TT + t) * 256 + kc * 4 + q] = v;
    }
    __syncthreads();

    const float4 hv = ((const float4*)h_s)[ln];
    for (int s = wv; s < SS; s += 4) {
      const float4 ev = ((const float4*)(enc_s + s * HH))[ln];
      float p = hv.x * ev.x + hv.y * ev.y + hv.z * ev.z + hv.w * ev.w;
      p = wsum(p);
      if (ln == 0) at_s[s] = p * 0.0625f;
    }
    __syncthreads();
    if (wv == 0) {
      const float v0 = (ln < len) ? at_s[ln] : -3.0e38f;
      const bool has1 = (ln < 8) && (64 + ln < len);
      const float v1 = has1 ? at_s[64 + ln] : -3.0e38f;
      const float m = wmax(fmaxf(v0, v1));
      const float e0 = (ln < len) ? __expf(v0 - m) : 0.f;
      const float e1 = has1 ? __expf(v1 - m) : 0.f;
      const float inv = 1.f / wsum(e0 + e1);
      at_s[ln] = e0 * inv;
      if (ln < 8) at_s[64 + ln] = e1 * inv;
    }
    __syncthreads();
    float acc = 0.f;
#pragma unroll 8
    for (int s = 0; s < SS; ++s) acc += at_s[s] * enc_s[s * HH + tid];
    hcat[(size_t)(b * TT + t) * KK + HH + tid] = f2bf(acc);
  }
}

// ------------------------------------------------------------------ vocab GEMM (validated)
__launch_bounds__(256)
__global__ void gemm_kernel(const unsigned short* __restrict__ A,
                            const unsigned short* __restrict__ Bw,
                            const float* __restrict__ blin,
                            float* __restrict__ out) {
  __shared__ __align__(16) unsigned short As[128 * 32];
  __shared__ __align__(16) unsigned short Bs[128 * 32];

  const int bid = blockIdx.x;
  const int mt = bid % 36;
  const int nt = bid / 36;
  const int m0 = mt * 128, n0 = nt * 128;
  const int tid = threadIdx.x;
  const int ln = tid & 63;
  const int w  = tid >> 6;
  const int wm = w >> 1, wn = w & 1;

  const char* Ab = (const char*)(A + (size_t)m0 * KK);
  const char* Bb = (const char*)(Bw + (size_t)n0 * KK);

  const int o0 = tid * 16;
  const int o1 = o0 + 4096;
  const int r0 = o0 >> 6, c0b = o0 & 63;
  const int r1 = o1 >> 6, c1b = o1 & 63;

  f32x4 acc[4][4] = {};

  float bs[4];
#pragma unroll
  for (int fn = 0; fn < 4; ++fn) bs[fn] = blin[n0 + wn * 64 + fn * 16 + (ln & 15)];

  for (int kt = 0; kt < 16; ++kt) {
    const int kb = kt * 64;
    g2l16(Ab + (size_t)r0 * (KK * 2) + kb + c0b, (char*)As + o0);
    g2l16(Ab + (size_t)r1 * (KK * 2) + kb + c1b, (char*)As + o1);
    g2l16(Bb + (size_t)r0 * (KK * 2) + kb + c0b, (char*)Bs + o0);
    g2l16(Bb + (size_t)r1 * (KK * 2) + kb + c1b, (char*)Bs + o1);
    __syncthreads();

    short8 af[4], bf[4];
#pragma unroll
    for (int f = 0; f < 4; ++f) {
      af[f] = *(const short8*)&As[(wm * 64 + f * 16 + (ln & 15)) * 32 + (ln >> 4) * 8];
      bf[f] = *(const short8*)&Bs[(wn * 64 + f * 16 + (ln & 15)) * 32 + (ln >> 4) * 8];
    }
#pragma unroll
    for (int fm = 0; fm < 4; ++fm)
#pragma unroll
      for (int fn = 0; fn < 4; ++fn)
        acc[fm][fn] = __builtin_amdgcn_mfma_f32_16x16x32_bf16(af[fm], bf[fn], acc[fm][fn], 0, 0, 0);
    __syncthreads();
  }

#pragma unroll
  for (int fm = 0; fm < 4; ++fm) {
    const int mrow = m0 + wm * 64 + fm * 16 + (ln >> 4) * 4;
#pragma unroll
    for (int fn = 0; fn < 4; ++fn) {
      const int n = n0 + wn * 64 + fn * 16 + (ln & 15);
      float* cp = out + (size_t)mrow * VV + n;
#pragma unroll
      for (int r = 0; r < 4; ++r) cp[(size_t)r * VV] = acc[fm][fn][r] + bs[fn];
    }
  }
}

// ------------------------------------------------------------------
extern "C" void kernel_launch(void* const* d_in, const int* in_sizes, int n_in,
                              void* d_out, int out_size, void* d_ws, size_t ws_size,
                              hipStream_t stream) {
  const int*   tok  = (const int*)  d_in[0];
  const float* enc  = (const float*)d_in[1];
  const int*   lens = (const int*)  d_in[2];
  const float* h0   = (const float*)d_in[3];
  const float* c0   = (const float*)d_in[4];
  const float* emb  = (const float*)d_in[5];
  const float* Wih  = (const float*)d_in[6];
  const float* Whh  = (const float*)d_in[7];
  const float* bih  = (const float*)d_in[8];
  const float* bhh  = (const float*)d_in[9];
  const float* Wlin = (const float*)d_in[10];
  const float* blin = (const float*)d_in[11];

  char* ws = (char*)d_ws;
  unsigned short* wlin16 = (unsigned short*)(ws);               // 32,768,000 B
  unsigned short* hcat   = (unsigned short*)(ws + 32768000);    //  4,718,592 B
  uint4*          xembt  = (uint4*)         (ws + 37486592);    //  1,179,648 B
  uint4*          hex    = (uint4*)         (ws + 38666240);    //  2,392,064 B
  unsigned int*   flags  = (unsigned int*)  (ws + 41058304);    //  16 B
  unsigned int*   elect  = (unsigned int*)  (ws + 41058320);    //  36 B
  float* out = (float*)d_out;

  hipMemsetAsync(flags, 0, 64, stream);
  gather_kernel<<<(TT * 16 * 64 + 255) / 256, 256, 0, stream>>>(tok, emb, xembt);
  lstm_kernel<<<64, 512, 0, stream>>>(h0, c0, Wih, Whh, bih, bhh, xembt, hex, flags, elect);
  attn_kernel<<<BB * 4, 256, 0, stream>>>(enc, lens, (const unsigned int*)hex, hcat);
  cvt_kernel<<<2048, 256, 0, stream>>>(Wlin, wlin16, (VV * KK) / 4);
  gemm_kernel<<<36 * 250, 256, 0, stream>>>(hcat, wlin16, blin, out);
}